// Round 9
// baseline (177.737 us; speedup 1.0000x reference)
//
#include <hip/hip_runtime.h>
#include <math.h>

#define D_DIM 192
#define H_DIM 224
#define W_DIM 192
#define TILE_ROWS 4              // j-rows per block (224 % 4 == 0 -> same i)
#define BLOCK 192                // one thread per k -> no div/mod in hot path
#define NUM_XCD 8

// ---------------------------------------------------------------------------
// R13: occupancy lever under the (now-measured) latency-bound model.
// R12 clock probe: 12000 dependent FMAs in 55.5 us -> f ~= 0.95 GHz (4cyc
// dep-FMA latency) — the core clock is ~1 GHz during this workload, not 2.4.
// With that, ALL rounds close under one model: L2-latency-bound gathers,
//   time = requests x latency / outstanding:
//   R3: 21 waves/CU x 16 req = 336 outst -> 113ns implied latency = L2 ✓
//   R6: 10x32 = 320 -> same 44 us ✓ ; R7 split fence: 13x16=208 -> 48 us ✓
// Lever: outstanding = waves x 16. Occupancy stuck at ~60% with no resource
// limiter -> suspect the __launch_bounds__(192,4) waves/EU floor is all the
// scheduler targets. Raise to 8 (VGPR 36 << 64 budget, no spill).
// Clock probe removed (diagnostic done). Body = proven R3 structure:
// 16 float2 gathers, single 16-operand MLP fence, fused T, XCD slab swizzle.
// ---------------------------------------------------------------------------

__device__ inline void mm4(const float* A, const float* B, float* C) {
#pragma unroll
    for (int r = 0; r < 4; ++r)
#pragma unroll
        for (int c = 0; c < 4; ++c) {
            float s = 0.f;
#pragma unroll
            for (int t = 0; t < 4; ++t) s += A[r * 4 + t] * B[t * 4 + c];
            C[r * 4 + c] = s;
        }
}

// Closed-form adjugate inverse: fully static indexing -> stays in VGPRs.
__device__ inline void inv4(const float* m, float* invOut) {
    float inv[16];
    inv[0]  =  m[5]*m[10]*m[15] - m[5]*m[11]*m[14] - m[9]*m[6]*m[15]
             + m[9]*m[7]*m[14] + m[13]*m[6]*m[11] - m[13]*m[7]*m[10];
    inv[4]  = -m[4]*m[10]*m[15] + m[4]*m[11]*m[14] + m[8]*m[6]*m[15]
             - m[8]*m[7]*m[14] - m[12]*m[6]*m[11] + m[12]*m[7]*m[10];
    inv[8]  =  m[4]*m[9]*m[15] - m[4]*m[11]*m[13] - m[8]*m[5]*m[15]
             + m[8]*m[7]*m[13] + m[12]*m[5]*m[11] - m[12]*m[7]*m[9];
    inv[12] = -m[4]*m[9]*m[14] + m[4]*m[10]*m[13] + m[8]*m[5]*m[14]
             - m[8]*m[6]*m[13] - m[12]*m[5]*m[10] + m[12]*m[6]*m[9];
    inv[1]  = -m[1]*m[10]*m[15] + m[1]*m[11]*m[14] + m[9]*m[2]*m[15]
             - m[9]*m[3]*m[14] - m[13]*m[2]*m[11] + m[13]*m[3]*m[10];
    inv[5]  =  m[0]*m[10]*m[15] - m[0]*m[11]*m[14] - m[8]*m[2]*m[15]
             + m[8]*m[3]*m[14] + m[12]*m[2]*m[11] - m[12]*m[3]*m[10];
    inv[9]  = -m[0]*m[9]*m[15] + m[0]*m[11]*m[13] + m[8]*m[1]*m[15]
             - m[8]*m[3]*m[13] - m[12]*m[1]*m[11] + m[12]*m[3]*m[9];
    inv[13] =  m[0]*m[9]*m[14] - m[0]*m[10]*m[13] - m[8]*m[1]*m[14]
             + m[8]*m[2]*m[13] + m[12]*m[1]*m[10] - m[12]*m[2]*m[9];
    inv[2]  =  m[1]*m[6]*m[15] - m[1]*m[7]*m[14] - m[5]*m[2]*m[15]
             + m[5]*m[3]*m[14] + m[13]*m[2]*m[7] - m[13]*m[3]*m[6];
    inv[6]  = -m[0]*m[6]*m[15] + m[0]*m[7]*m[14] + m[4]*m[2]*m[15]
             - m[4]*m[3]*m[14] - m[12]*m[2]*m[7] + m[12]*m[3]*m[6];
    inv[10] =  m[0]*m[5]*m[15] - m[0]*m[7]*m[13] - m[4]*m[1]*m[15]
             + m[4]*m[3]*m[13] + m[12]*m[1]*m[7] - m[12]*m[3]*m[5];
    inv[14] = -m[0]*m[5]*m[14] + m[0]*m[6]*m[13] + m[4]*m[1]*m[14]
             - m[4]*m[2]*m[13] - m[12]*m[1]*m[6] + m[12]*m[2]*m[5];
    inv[3]  = -m[1]*m[6]*m[11] + m[1]*m[7]*m[10] + m[5]*m[2]*m[11]
             - m[5]*m[3]*m[10] - m[9]*m[2]*m[7] + m[9]*m[3]*m[6];
    inv[7]  =  m[0]*m[6]*m[11] - m[0]*m[7]*m[10] - m[4]*m[2]*m[11]
             + m[4]*m[3]*m[10] + m[8]*m[2]*m[7] - m[8]*m[3]*m[6];
    inv[11] = -m[0]*m[5]*m[11] + m[0]*m[7]*m[9] + m[4]*m[1]*m[11]
             - m[4]*m[3]*m[9] - m[8]*m[1]*m[7] + m[8]*m[3]*m[5];
    inv[15] =  m[0]*m[5]*m[10] - m[0]*m[6]*m[9] - m[4]*m[1]*m[10]
             + m[4]*m[2]*m[9] + m[8]*m[1]*m[6] - m[8]*m[2]*m[5];

    float det = m[0]*inv[0] + m[1]*inv[4] + m[2]*inv[8] + m[3]*inv[12];
    det = 1.0f / det;
#pragma unroll
    for (int i = 0; i < 16; ++i) invOut[i] = inv[i] * det;
}

typedef float vf4 __attribute__((ext_vector_type(4)));
typedef float vf2 __attribute__((ext_vector_type(2)));

__device__ inline float rfl(float x) {
    return __int_as_float(__builtin_amdgcn_readfirstlane(__float_as_int(x)));
}

__global__ __launch_bounds__(BLOCK, 8) void resample_kernel(
    const float* __restrict__ vol,
    const float* __restrict__ ang,
    const float* __restrict__ tr,
    const float* __restrict__ scl,
    const float* __restrict__ ref_v2r,
    const float* __restrict__ flo_v2r,
    float* __restrict__ out) {

    constexpr int TILES_PER_I = H_DIM / TILE_ROWS;            // 56
    constexpr int NBLK = D_DIM * TILES_PER_I;                 // 10752
    constexpr int PER_XCD = NBLK / NUM_XCD;                   // 1344

    __shared__ float sT[12];

    // ---- Fused T composition (thread 0; same code -> same rounding) ----
    if (threadIdx.x == 0) {
        const float a0 = ang[0], a1 = ang[1], a2 = ang[2];
        const float tr0 = tr[0], tr1 = tr[1], tr2 = tr[2];
        const float sc0 = scl[0], sc1 = scl[1], sc2 = scl[2];
        vf4 refv[4], flov[4];
#pragma unroll
        for (int r = 0; r < 4; ++r) {
            refv[r] = *(const vf4*)(ref_v2r + 4 * r);
            flov[r] = *(const vf4*)(flo_v2r + 4 * r);
        }
        float refm[16], flom[16];
#pragma unroll
        for (int r = 0; r < 4; ++r)
#pragma unroll
            for (int c = 0; c < 4; ++c) {
                refm[r * 4 + c] = refv[r][c];
                flom[r * 4 + c] = flov[r][c];
            }

        const float cogx = 96.f, cogy = 112.f, cogz = 96.f;
        float cx = cosf(a0), sx = sinf(a0);
        float cy = cosf(a1), sy = sinf(a1);
        float cz = cosf(a2), sz = sinf(a2);

        float Rx[9] = {1, 0, 0, 0, cx, -sx, 0, sx, cx};
        float Ry[9] = {cy, 0, sy, 0, 1, 0, -sy, 0, cy};
        float Rz[9] = {cz, -sz, 0, sz, cz, 0, 0, 0, 1};
        float Ryz[9], R[9];
#pragma unroll
        for (int r = 0; r < 3; ++r)
#pragma unroll
            for (int c = 0; c < 3; ++c) {
                float s = 0.f;
#pragma unroll
                for (int t = 0; t < 3; ++t) s += Ry[r * 3 + t] * Rz[t * 3 + c];
                Ryz[r * 3 + c] = s;
            }
#pragma unroll
        for (int r = 0; r < 3; ++r)
#pragma unroll
            for (int c = 0; c < 3; ++c) {
                float s = 0.f;
#pragma unroll
                for (int t = 0; t < 3; ++t) s += Rx[r * 3 + t] * Ryz[t * 3 + c];
                R[r * 3 + c] = s;
            }

        float s0 = expf(sc0), s1 = expf(sc1), s2 = expf(sc2);

        float Tc[16]   = {1,0,0,-cogx, 0,1,0,-cogy, 0,0,1,-cogz, 0,0,0,1};
        float Tci[16]  = {1,0,0, cogx, 0,1,0, cogy, 0,0,1, cogz, 0,0,0,1};
        float Tsc[16]  = {s0,0,0,0, 0,s1,0,0, 0,0,s2,0, 0,0,0,1};
        float Ttr[16]  = {1,0,0,tr0, 0,1,0,tr1, 0,0,1,tr2, 0,0,0,1};
        float Trot[16] = {R[0],R[1],R[2],0, R[3],R[4],R[5],0,
                          R[6],R[7],R[8],0, 0,0,0,1};

        float m1[16], m2[16], m3[16], Trig[16];
        mm4(Tci, Ttr, m1);
        mm4(m1, Trot, m2);
        mm4(m2, Tsc, m3);
        mm4(m3, Tc, Trig);

        float floinv[16], m4v[16], T[16];
        inv4(flom, floinv);
        mm4(floinv, Trig, m4v);
        mm4(m4v, refm, T);

#pragma unroll
        for (int q = 0; q < 12; ++q) sT[q] = T[q];
    }
    __syncthreads();

    // Wave-uniform T -> SGPRs via readfirstlane.
    const float t00 = rfl(sT[0]),  t01 = rfl(sT[1]);
    const float t02 = rfl(sT[2]),  t03 = rfl(sT[3]);
    const float t10 = rfl(sT[4]),  t11 = rfl(sT[5]);
    const float t12 = rfl(sT[6]),  t13 = rfl(sT[7]);
    const float t20 = rfl(sT[8]),  t21 = rfl(sT[9]);
    const float t22 = rfl(sT[10]), t23 = rfl(sT[11]);

    const int b = blockIdx.x;
    const int xcd = b & (NUM_XCD - 1);
    const int q = b >> 3;
    const int sb = xcd * PER_XCD + q;          // slab-contiguous tile index
    const int i = sb / TILES_PER_I;
    const int jbase = (sb - i * TILES_PER_I) * TILE_ROWS;
    const int k = threadIdx.x;                 // 0..191

    const float fi = (float)i;
    const float fk = (float)k;

    vf2  p00[TILE_ROWS], p10[TILE_ROWS], p01[TILE_ROWS], p11[TILE_ROWS];
    float wi[TILE_ROWS], wj[TILE_ROWS], wk[TILE_ROWS];
    int   sel[TILE_ROWS];
    bool  okr[TILE_ROWS];

    // ---- Phase 1: addresses + ALL 16 float2 gathers issued ----
#pragma unroll
    for (int r = 0; r < TILE_ROWS; ++r) {
        const float fj = (float)(jbase + r);
        // EXACT R1 expression — do not reassociate (ok-mask boundary).
        const float di = t00 * fi + t01 * fj + t02 * fk + t03;
        const float dj = t10 * fi + t11 * fj + t12 * fk + t13;
        const float dk = t20 * fi + t21 * fj + t22 * fk + t23;

        okr[r] = (di > 0.f) & (dj > 0.f) & (dk > 0.f) &
                 (di <= (float)(D_DIM - 1)) &
                 (dj <= (float)(H_DIM - 1)) &
                 (dk <= (float)(W_DIM - 1));

        float ffi = fminf(fmaxf(floorf(di), 0.f), (float)(D_DIM - 1));
        float ffj = fminf(fmaxf(floorf(dj), 0.f), (float)(H_DIM - 1));
        float ffk = fminf(fmaxf(floorf(dk), 0.f), (float)(W_DIM - 1));

        wi[r] = di - ffi; wj[r] = dj - ffj; wk[r] = dk - ffk;

        const int i0 = (int)ffi, j0 = (int)ffj, k0 = (int)ffk;
        const int i1 = min(i0 + 1, D_DIM - 1);
        const int j1 = min(j0 + 1, H_DIM - 1);
        const int koff = min(k0, W_DIM - 2);   // 8B load stays in-bounds
        sel[r] = k0 - koff;                    // 1 iff k0 == W-1

        const int base00 = (i0 * H_DIM + j0) * W_DIM + koff;
        const int base01 = (i0 * H_DIM + j1) * W_DIM + koff;
        const int base10 = (i1 * H_DIM + j0) * W_DIM + koff;
        const int base11 = (i1 * H_DIM + j1) * W_DIM + koff;

        p00[r] = *(const vf2*)(vol + base00);
        p10[r] = *(const vf2*)(vol + base10);
        p01[r] = *(const vf2*)(vol + base01);
        p11[r] = *(const vf2*)(vol + base11);
    }

    // ---- MLP fence: all 16 load results live in VGPRs here ----
    asm volatile(""
        : "+v"(p00[0]), "+v"(p10[0]), "+v"(p01[0]), "+v"(p11[0]),
          "+v"(p00[1]), "+v"(p10[1]), "+v"(p01[1]), "+v"(p11[1]),
          "+v"(p00[2]), "+v"(p10[2]), "+v"(p01[2]), "+v"(p11[2]),
          "+v"(p00[3]), "+v"(p10[3]), "+v"(p01[3]), "+v"(p11[3]));

    // ---- Phase 2: interpolate + coalesced nontemporal store ----
#pragma unroll
    for (int r = 0; r < TILE_ROWS; ++r) {
        const float c000 = sel[r] ? p00[r].y : p00[r].x;
        const float c100 = sel[r] ? p10[r].y : p10[r].x;
        const float c010 = sel[r] ? p01[r].y : p01[r].x;
        const float c110 = sel[r] ? p11[r].y : p11[r].x;
        const float c001 = p00[r].y;
        const float c101 = p10[r].y;
        const float c011 = p01[r].y;
        const float c111 = p11[r].y;

        const float omwi = 1.f - wi[r], omwj = 1.f - wj[r], omwk = 1.f - wk[r];
        const float val = ((c000 * omwi + c100 * wi[r]) * omwj +
                           (c010 * omwi + c110 * wi[r]) * wj[r]) * omwk +
                          ((c001 * omwi + c101 * wi[r]) * omwj +
                           (c011 * omwi + c111 * wi[r]) * wj[r]) * wk[r];
        const float res = okr[r] ? val : 0.f;
        __builtin_nontemporal_store(res, &out[(i * H_DIM + (jbase + r)) * W_DIM + k]);
    }
}

// ---------------------------------------------------------------------------

extern "C" void kernel_launch(void* const* d_in, const int* in_sizes, int n_in,
                              void* d_out, int out_size, void* d_ws, size_t ws_size,
                              hipStream_t stream) {
    const float* image_targ  = (const float*)d_in[0];
    const float* angle       = (const float*)d_in[1];
    const float* translation = (const float*)d_in[2];
    const float* scaling     = (const float*)d_in[3];
    const float* ref_v2r     = (const float*)d_in[4];
    const float* flo_v2r     = (const float*)d_in[5];
    float* out = (float*)d_out;
    (void)d_ws; (void)ws_size;

    const int nblk = D_DIM * (H_DIM / TILE_ROWS);  // 10752
    resample_kernel<<<nblk, BLOCK, 0, stream>>>(image_targ, angle, translation,
                                                scaling, ref_v2r, flo_v2r, out);
}

// Round 10
// 115.649 us; speedup vs baseline: 1.5369x; 1.5369x over previous
//
#include <hip/hip_runtime.h>
#include <math.h>

#define D_DIM 192
#define H_DIM 224
#define W_DIM 192
#define TILE_ROWS 8              // j-rows per block (224 % 8 == 0 -> same i)
#define BLOCK 192                // one thread per k -> no div/mod in hot path
#define NUM_XCD 8

// ---------------------------------------------------------------------------
// R14: 32-deep load batch via two CHAINED group fences (fixing R7's split and
// R13's spill).
// Model (R12 probe: core clock ~1 GHz): L2-latency-bound gathers,
//   time = requests x latency / outstanding, outstanding = waves x in-flight.
// R13 evidence FOR the model: spill traffic raised outstanding -> highest
// delivered BW of any round (1.63 TB/s) — but VGPR cap 32 (launch_bounds 8)
// spilled the batch (WRITE 32->117 MB) and doubled duration.
// This round: TILE_ROWS=8 -> 32 float2 gathers/thread. Two 16-operand asm
// fences (R3-proven form), each with "memory" clobber:
//   - loads are memory ops -> group-1 loads CANNOT sink below fence-0
//     => all 32 issued before the first wait (vmcnt(16) counted, not 0)
//   - consume-0 reads fence-0 outputs -> cannot hoist; its stores cannot
//     cross fence-1 ("memory") -> phases stay clean, 16 stay in flight
//     through consume-0.
// VGPR budget: 64 results + 24 weights + 2 packed masks + temps ~= 100 < 128
// cap (launch_bounds(192,4)) -> no spill. TRIPWIRE: WRITE_SIZE must stay
// 32256 KB (117 MB in R13 = spill signature).
// Numerics: per-voxel di/dj/dk, ok-mask, weights, taps byte-identical.
// Addresses strength-reduced (R11-validated: same integers, passed).
// ---------------------------------------------------------------------------

__device__ inline void mm4(const float* A, const float* B, float* C) {
#pragma unroll
    for (int r = 0; r < 4; ++r)
#pragma unroll
        for (int c = 0; c < 4; ++c) {
            float s = 0.f;
#pragma unroll
            for (int t = 0; t < 4; ++t) s += A[r * 4 + t] * B[t * 4 + c];
            C[r * 4 + c] = s;
        }
}

// Closed-form adjugate inverse: fully static indexing -> stays in VGPRs.
__device__ inline void inv4(const float* m, float* invOut) {
    float inv[16];
    inv[0]  =  m[5]*m[10]*m[15] - m[5]*m[11]*m[14] - m[9]*m[6]*m[15]
             + m[9]*m[7]*m[14] + m[13]*m[6]*m[11] - m[13]*m[7]*m[10];
    inv[4]  = -m[4]*m[10]*m[15] + m[4]*m[11]*m[14] + m[8]*m[6]*m[15]
             - m[8]*m[7]*m[14] - m[12]*m[6]*m[11] + m[12]*m[7]*m[10];
    inv[8]  =  m[4]*m[9]*m[15] - m[4]*m[11]*m[13] - m[8]*m[5]*m[15]
             + m[8]*m[7]*m[13] + m[12]*m[5]*m[11] - m[12]*m[7]*m[9];
    inv[12] = -m[4]*m[9]*m[14] + m[4]*m[10]*m[13] + m[8]*m[5]*m[14]
             - m[8]*m[6]*m[13] - m[12]*m[5]*m[10] + m[12]*m[6]*m[9];
    inv[1]  = -m[1]*m[10]*m[15] + m[1]*m[11]*m[14] + m[9]*m[2]*m[15]
             - m[9]*m[3]*m[14] - m[13]*m[2]*m[11] + m[13]*m[3]*m[10];
    inv[5]  =  m[0]*m[10]*m[15] - m[0]*m[11]*m[14] - m[8]*m[2]*m[15]
             + m[8]*m[3]*m[14] + m[12]*m[2]*m[11] - m[12]*m[3]*m[10];
    inv[9]  = -m[0]*m[9]*m[15] + m[0]*m[11]*m[13] + m[8]*m[1]*m[15]
             - m[8]*m[3]*m[13] - m[12]*m[1]*m[11] + m[12]*m[3]*m[9];
    inv[13] =  m[0]*m[9]*m[14] - m[0]*m[10]*m[13] - m[8]*m[1]*m[14]
             + m[8]*m[2]*m[13] + m[12]*m[1]*m[10] - m[12]*m[2]*m[9];
    inv[2]  =  m[1]*m[6]*m[15] - m[1]*m[7]*m[14] - m[5]*m[2]*m[15]
             + m[5]*m[3]*m[14] + m[13]*m[2]*m[7] - m[13]*m[3]*m[6];
    inv[6]  = -m[0]*m[6]*m[15] + m[0]*m[7]*m[14] + m[4]*m[2]*m[15]
             - m[4]*m[3]*m[14] - m[12]*m[2]*m[7] + m[12]*m[3]*m[6];
    inv[10] =  m[0]*m[5]*m[15] - m[0]*m[7]*m[13] - m[4]*m[1]*m[15]
             + m[4]*m[3]*m[13] + m[12]*m[1]*m[7] - m[12]*m[3]*m[5];
    inv[14] = -m[0]*m[5]*m[14] + m[0]*m[6]*m[13] + m[4]*m[1]*m[14]
             - m[4]*m[2]*m[13] - m[12]*m[1]*m[6] + m[12]*m[2]*m[5];
    inv[3]  = -m[1]*m[6]*m[11] + m[1]*m[7]*m[10] + m[5]*m[2]*m[11]
             - m[5]*m[3]*m[10] - m[9]*m[2]*m[7] + m[9]*m[3]*m[6];
    inv[7]  =  m[0]*m[6]*m[11] - m[0]*m[7]*m[10] - m[4]*m[2]*m[11]
             + m[4]*m[3]*m[10] + m[8]*m[2]*m[7] - m[8]*m[3]*m[6];
    inv[11] = -m[0]*m[5]*m[11] + m[0]*m[7]*m[9] + m[4]*m[1]*m[11]
             - m[4]*m[3]*m[9] - m[8]*m[1]*m[7] + m[8]*m[3]*m[5];
    inv[15] =  m[0]*m[5]*m[10] - m[0]*m[6]*m[9] - m[4]*m[1]*m[10]
             + m[4]*m[2]*m[9] + m[8]*m[1]*m[6] - m[8]*m[2]*m[5];

    float det = m[0]*inv[0] + m[1]*inv[4] + m[2]*inv[8] + m[3]*inv[12];
    det = 1.0f / det;
#pragma unroll
    for (int i = 0; i < 16; ++i) invOut[i] = inv[i] * det;
}

typedef float vf4 __attribute__((ext_vector_type(4)));
typedef float vf2 __attribute__((ext_vector_type(2)));

__device__ inline float rfl(float x) {
    return __int_as_float(__builtin_amdgcn_readfirstlane(__float_as_int(x)));
}

__global__ __launch_bounds__(BLOCK, 4) void resample_kernel(
    const float* __restrict__ vol,
    const float* __restrict__ ang,
    const float* __restrict__ tr,
    const float* __restrict__ scl,
    const float* __restrict__ ref_v2r,
    const float* __restrict__ flo_v2r,
    float* __restrict__ out) {

    constexpr int TILES_PER_I = H_DIM / TILE_ROWS;            // 28
    constexpr int NBLK = D_DIM * TILES_PER_I;                 // 5376
    constexpr int PER_XCD = NBLK / NUM_XCD;                   // 672

    __shared__ float sT[12];

    // ---- Fused T composition (thread 0; same code -> same rounding) ----
    if (threadIdx.x == 0) {
        const float a0 = ang[0], a1 = ang[1], a2 = ang[2];
        const float tr0 = tr[0], tr1 = tr[1], tr2 = tr[2];
        const float sc0 = scl[0], sc1 = scl[1], sc2 = scl[2];
        vf4 refv[4], flov[4];
#pragma unroll
        for (int r = 0; r < 4; ++r) {
            refv[r] = *(const vf4*)(ref_v2r + 4 * r);
            flov[r] = *(const vf4*)(flo_v2r + 4 * r);
        }
        float refm[16], flom[16];
#pragma unroll
        for (int r = 0; r < 4; ++r)
#pragma unroll
            for (int c = 0; c < 4; ++c) {
                refm[r * 4 + c] = refv[r][c];
                flom[r * 4 + c] = flov[r][c];
            }

        const float cogx = 96.f, cogy = 112.f, cogz = 96.f;
        float cx = cosf(a0), sx = sinf(a0);
        float cy = cosf(a1), sy = sinf(a1);
        float cz = cosf(a2), sz = sinf(a2);

        float Rx[9] = {1, 0, 0, 0, cx, -sx, 0, sx, cx};
        float Ry[9] = {cy, 0, sy, 0, 1, 0, -sy, 0, cy};
        float Rz[9] = {cz, -sz, 0, sz, cz, 0, 0, 0, 1};
        float Ryz[9], R[9];
#pragma unroll
        for (int r = 0; r < 3; ++r)
#pragma unroll
            for (int c = 0; c < 3; ++c) {
                float s = 0.f;
#pragma unroll
                for (int t = 0; t < 3; ++t) s += Ry[r * 3 + t] * Rz[t * 3 + c];
                Ryz[r * 3 + c] = s;
            }
#pragma unroll
        for (int r = 0; r < 3; ++r)
#pragma unroll
            for (int c = 0; c < 3; ++c) {
                float s = 0.f;
#pragma unroll
                for (int t = 0; t < 3; ++t) s += Rx[r * 3 + t] * Ryz[t * 3 + c];
                R[r * 3 + c] = s;
            }

        float s0 = expf(sc0), s1 = expf(sc1), s2 = expf(sc2);

        float Tc[16]   = {1,0,0,-cogx, 0,1,0,-cogy, 0,0,1,-cogz, 0,0,0,1};
        float Tci[16]  = {1,0,0, cogx, 0,1,0, cogy, 0,0,1, cogz, 0,0,0,1};
        float Tsc[16]  = {s0,0,0,0, 0,s1,0,0, 0,0,s2,0, 0,0,0,1};
        float Ttr[16]  = {1,0,0,tr0, 0,1,0,tr1, 0,0,1,tr2, 0,0,0,1};
        float Trot[16] = {R[0],R[1],R[2],0, R[3],R[4],R[5],0,
                          R[6],R[7],R[8],0, 0,0,0,1};

        float m1[16], m2[16], m3[16], Trig[16];
        mm4(Tci, Ttr, m1);
        mm4(m1, Trot, m2);
        mm4(m2, Tsc, m3);
        mm4(m3, Tc, Trig);

        float floinv[16], m4v[16], T[16];
        inv4(flom, floinv);
        mm4(floinv, Trig, m4v);
        mm4(m4v, refm, T);

#pragma unroll
        for (int q = 0; q < 12; ++q) sT[q] = T[q];
    }
    __syncthreads();

    // Wave-uniform T -> SGPRs via readfirstlane.
    const float t00 = rfl(sT[0]),  t01 = rfl(sT[1]);
    const float t02 = rfl(sT[2]),  t03 = rfl(sT[3]);
    const float t10 = rfl(sT[4]),  t11 = rfl(sT[5]);
    const float t12 = rfl(sT[6]),  t13 = rfl(sT[7]);
    const float t20 = rfl(sT[8]),  t21 = rfl(sT[9]);
    const float t22 = rfl(sT[10]), t23 = rfl(sT[11]);

    const int b = blockIdx.x;
    const int xcd = b & (NUM_XCD - 1);
    const int q = b >> 3;
    const int sb = xcd * PER_XCD + q;          // slab-contiguous tile index
    const int i = sb / TILES_PER_I;
    const int jbase = (sb - i * TILES_PER_I) * TILE_ROWS;
    const int k = threadIdx.x;                 // 0..191

    const float fi = (float)i;
    const float fk = (float)k;

    vf2  p00[TILE_ROWS], p10[TILE_ROWS], p01[TILE_ROWS], p11[TILE_ROWS];
    float wi[TILE_ROWS], wj[TILE_ROWS], wk[TILE_ROWS];
    int selmask = 0;   // bit r: k0 == W-1 for row r
    int okmask  = 0;   // bit r: ok-mask for row r

    // ---- Phase 1: addresses + ALL 32 float2 gathers issued ----
#pragma unroll
    for (int r = 0; r < TILE_ROWS; ++r) {
        const float fj = (float)(jbase + r);
        // EXACT R1 expression — do not reassociate (ok-mask boundary).
        const float di = t00 * fi + t01 * fj + t02 * fk + t03;
        const float dj = t10 * fi + t11 * fj + t12 * fk + t13;
        const float dk = t20 * fi + t21 * fj + t22 * fk + t23;

        const bool ok = (di > 0.f) & (dj > 0.f) & (dk > 0.f) &
                        (di <= (float)(D_DIM - 1)) &
                        (dj <= (float)(H_DIM - 1)) &
                        (dk <= (float)(W_DIM - 1));
        okmask |= ((int)ok) << r;

        float ffi = fminf(fmaxf(floorf(di), 0.f), (float)(D_DIM - 1));
        float ffj = fminf(fmaxf(floorf(dj), 0.f), (float)(H_DIM - 1));
        float ffk = fminf(fmaxf(floorf(dk), 0.f), (float)(W_DIM - 1));

        wi[r] = di - ffi; wj[r] = dj - ffj; wk[r] = dk - ffk;

        const int i0 = (int)ffi, j0 = (int)ffj, k0 = (int)ffk;
        const int i1 = min(i0 + 1, D_DIM - 1);
        const int j1 = min(j0 + 1, H_DIM - 1);
        const int koff = min(k0, W_DIM - 2);   // 8B load stays in-bounds
        selmask |= (k0 - koff) << r;           // 1 iff k0 == W-1

        // Strength-reduced bases: identical integers (R11-validated).
        const int base00 = (i0 * H_DIM + j0) * W_DIM + koff;
        const int dj_off = (j1 - j0) * W_DIM;            // 0 or 192
        const int di_off = (i1 - i0) * (H_DIM * W_DIM);  // 0 or 43008

        p00[r] = *(const vf2*)(vol + base00);
        p10[r] = *(const vf2*)(vol + base00 + di_off);
        p01[r] = *(const vf2*)(vol + base00 + dj_off);
        p11[r] = *(const vf2*)(vol + base00 + di_off + dj_off);
    }

    // ---- Fence 0: rows 0-3 results live; "memory" pins rows 4-7's loads
    //      ABOVE this point (loads are memory ops) -> all 32 in flight;
    //      compiler waits vmcnt(16) here, group 1 stays outstanding. ----
    asm volatile(""
        : "+v"(p00[0]), "+v"(p10[0]), "+v"(p01[0]), "+v"(p11[0]),
          "+v"(p00[1]), "+v"(p10[1]), "+v"(p01[1]), "+v"(p11[1]),
          "+v"(p00[2]), "+v"(p10[2]), "+v"(p01[2]), "+v"(p11[2]),
          "+v"(p00[3]), "+v"(p10[3]), "+v"(p01[3]), "+v"(p11[3])
        :
        : "memory");

    // ---- Consume rows 0-3 (16 loads still in flight underneath) ----
#pragma unroll
    for (int r = 0; r < 4; ++r) {
        const bool sel = (selmask >> r) & 1;
        const float c000 = sel ? p00[r].y : p00[r].x;
        const float c100 = sel ? p10[r].y : p10[r].x;
        const float c010 = sel ? p01[r].y : p01[r].x;
        const float c110 = sel ? p11[r].y : p11[r].x;
        const float c001 = p00[r].y;
        const float c101 = p10[r].y;
        const float c011 = p01[r].y;
        const float c111 = p11[r].y;

        const float omwi = 1.f - wi[r], omwj = 1.f - wj[r], omwk = 1.f - wk[r];
        const float val = ((c000 * omwi + c100 * wi[r]) * omwj +
                           (c010 * omwi + c110 * wi[r]) * wj[r]) * omwk +
                          ((c001 * omwi + c101 * wi[r]) * omwj +
                           (c011 * omwi + c111 * wi[r]) * wj[r]) * wk[r];
        const float res = ((okmask >> r) & 1) ? val : 0.f;
        __builtin_nontemporal_store(res, &out[(i * H_DIM + (jbase + r)) * W_DIM + k]);
    }

    // ---- Fence 1: rows 4-7 results live (drains the remaining 16). ----
    asm volatile(""
        : "+v"(p00[4]), "+v"(p10[4]), "+v"(p01[4]), "+v"(p11[4]),
          "+v"(p00[5]), "+v"(p10[5]), "+v"(p01[5]), "+v"(p11[5]),
          "+v"(p00[6]), "+v"(p10[6]), "+v"(p01[6]), "+v"(p11[6]),
          "+v"(p00[7]), "+v"(p10[7]), "+v"(p01[7]), "+v"(p11[7])
        :
        : "memory");

    // ---- Consume rows 4-7 ----
#pragma unroll
    for (int r = 4; r < 8; ++r) {
        const bool sel = (selmask >> r) & 1;
        const float c000 = sel ? p00[r].y : p00[r].x;
        const float c100 = sel ? p10[r].y : p10[r].x;
        const float c010 = sel ? p01[r].y : p01[r].x;
        const float c110 = sel ? p11[r].y : p11[r].x;
        const float c001 = p00[r].y;
        const float c101 = p10[r].y;
        const float c011 = p01[r].y;
        const float c111 = p11[r].y;

        const float omwi = 1.f - wi[r], omwj = 1.f - wj[r], omwk = 1.f - wk[r];
        const float val = ((c000 * omwi + c100 * wi[r]) * omwj +
                           (c010 * omwi + c110 * wi[r]) * wj[r]) * omwk +
                          ((c001 * omwi + c101 * wi[r]) * omwj +
                           (c011 * omwi + c111 * wi[r]) * wj[r]) * wk[r];
        const float res = ((okmask >> r) & 1) ? val : 0.f;
        __builtin_nontemporal_store(res, &out[(i * H_DIM + (jbase + r)) * W_DIM + k]);
    }
}

// ---------------------------------------------------------------------------

extern "C" void kernel_launch(void* const* d_in, const int* in_sizes, int n_in,
                              void* d_out, int out_size, void* d_ws, size_t ws_size,
                              hipStream_t stream) {
    const float* image_targ  = (const float*)d_in[0];
    const float* angle       = (const float*)d_in[1];
    const float* translation = (const float*)d_in[2];
    const float* scaling     = (const float*)d_in[3];
    const float* ref_v2r     = (const float*)d_in[4];
    const float* flo_v2r     = (const float*)d_in[5];
    float* out = (float*)d_out;
    (void)d_ws; (void)ws_size;

    const int nblk = D_DIM * (H_DIM / TILE_ROWS);  // 5376
    resample_kernel<<<nblk, BLOCK, 0, stream>>>(image_targ, angle, translation,
                                                scaling, ref_v2r, flo_v2r, out);
}